// Round 1
// baseline (603.674 us; speedup 1.0000x reference)
//
#include <hip/hip_runtime.h>

#define N_NODES 20000
#define N_EDGES 320000
#define DATA_DIM 64
#define H 128

// ---------- tiny precompute: r = relu(b_msg); c = r @ Wu_m; bx = b_emb @ Wu_x ----------
__global__ void k_pre(const float* __restrict__ b_emb,
                      const float* __restrict__ b_msg,
                      const float* __restrict__ W_upd,
                      float* __restrict__ r, float* __restrict__ c,
                      float* __restrict__ bx) {
    int j = threadIdx.x; // 128
    __shared__ float rs[H];
    float rj = fmaxf(b_msg[j], 0.f);
    r[j] = rj;
    rs[j] = rj;
    __syncthreads();
    float cj = 0.f, bxj = 0.f;
    for (int k = 0; k < H; k++) {
        cj  += rs[k] * W_upd[k * H + j];            // Wu_m rows 0..127
        bxj += b_emb[k] * W_upd[(256 + k) * H + j]; // Wu_x rows 256..383
    }
    c[j] = cj;
    bx[j] = bxj;
}

// ---------- Wf = W_emb @ Wu_x  [64,128] ----------
__global__ void k_wf(const float* __restrict__ W_emb,
                     const float* __restrict__ W_upd,
                     float* __restrict__ Wf) {
    int d = blockIdx.x;  // 64 blocks
    int j = threadIdx.x; // 128
    __shared__ float es[H];
    es[j] = W_emb[d * H + j];
    __syncthreads();
    float acc = 0.f;
    for (int k = 0; k < H; k++)
        acc += es[k] * W_upd[(256 + k) * H + j];
    Wf[d * H + j] = acc;
}

// ---------- degree histogram over edge_dst ----------
__global__ void k_deg(const int* __restrict__ dst, int* __restrict__ deg) {
    int e = blockIdx.x * blockDim.x + threadIdx.x;
    if (e < N_EDGES) atomicAdd(&deg[dst[e]], 1);
}

// ---------- exclusive scan -> offs, cursor ----------
__global__ void k_scan(const int* __restrict__ deg, int* __restrict__ offs,
                       int* __restrict__ cursor) {
    __shared__ int buf[1024];
    int t = threadIdx.x;
    const int chunk = (N_NODES + 1023) / 1024; // 20
    int base = t * chunk;
    int s = 0;
    for (int i = 0; i < chunk; i++) {
        int idx = base + i;
        if (idx < N_NODES) s += deg[idx];
    }
    int val = s;
    for (int off = 1; off < 1024; off <<= 1) {
        buf[t] = val;
        __syncthreads();
        if (t >= off) val += buf[t - off];
        __syncthreads();
    }
    int run = val - s; // exclusive prefix of this chunk
    for (int i = 0; i < chunk; i++) {
        int idx = base + i;
        if (idx < N_NODES) {
            offs[idx] = run;
            cursor[idx] = run;
            run += deg[idx];
        }
    }
    if (t == 1023) offs[N_NODES] = val; // total == N_EDGES
}

// ---------- bucket-scatter edge ids by dst ----------
__global__ void k_scatter(const int* __restrict__ dst, int* __restrict__ cursor,
                          int* __restrict__ eperm) {
    int e = blockIdx.x * blockDim.x + threadIdx.x;
    if (e < N_EDGES) {
        int p = atomicAdd(&cursor[dst[e]], 1);
        eperm[p] = e;
    }
}

// ---------- xu = data @ Wf + bx   [N,128] ----------
__global__ void k_xu(const float* __restrict__ data, const float* __restrict__ Wf,
                     const float* __restrict__ bx, float* __restrict__ xu) {
    __shared__ float ds[4][DATA_DIM];
    int j = threadIdx.x; // 128
    float bxj = bx[j];
    for (int v0 = blockIdx.x * 4; v0 < N_NODES; v0 += gridDim.x * 4) {
        for (int idx = j; idx < 4 * DATA_DIM; idx += 128)
            ds[idx >> 6][idx & 63] = data[v0 * DATA_DIM + idx];
        __syncthreads();
        float a0 = 0, a1 = 0, a2 = 0, a3 = 0;
        for (int d = 0; d < DATA_DIM; d++) {
            float w = Wf[d * H + j];
            a0 += ds[0][d] * w;
            a1 += ds[1][d] * w;
            a2 += ds[2][d] * w;
            a3 += ds[3][d] * w;
        }
        xu[(v0 + 0) * H + j] = a0 + bxj;
        xu[(v0 + 1) * H + j] = a1 + bxj;
        xu[(v0 + 2) * H + j] = a2 + bxj;
        xu[(v0 + 3) * H + j] = a3 + bxj;
        __syncthreads();
    }
}

// ---------- h1 = tanh(deg*c + xu + b_upd) ----------
__global__ void k_h1(const float* __restrict__ xu, const int* __restrict__ deg,
                     const float* __restrict__ c, const float* __restrict__ b_upd,
                     float* __restrict__ h1) {
    int i = blockIdx.x * blockDim.x + threadIdx.x;
    if (i < N_NODES * H) {
        int v = i >> 7, j = i & 127;
        h1[i] = tanhf((float)deg[v] * c[j] + xu[i] + b_upd[j]);
    }
}

// ---------- A = h1 @ Wm_dst ; B = h1 @ Wm_src ----------
__global__ void k_ab(const float* __restrict__ h1, const float* __restrict__ W_msg,
                     float* __restrict__ A, float* __restrict__ B) {
    __shared__ float hs[4][H];
    int j = threadIdx.x; // 128
    for (int v0 = blockIdx.x * 4; v0 < N_NODES; v0 += gridDim.x * 4) {
        for (int idx = j; idx < 4 * H; idx += 128)
            hs[idx >> 7][idx & 127] = h1[v0 * H + idx];
        __syncthreads();
        float a0 = 0, a1 = 0, a2 = 0, a3 = 0;
        float b0 = 0, b1 = 0, b2 = 0, b3 = 0;
        for (int k = 0; k < H; k++) {
            float wd = W_msg[k * H + j];
            float ws = W_msg[(H + k) * H + j];
            float h0 = hs[0][k], h1v = hs[1][k], h2v = hs[2][k], h3v = hs[3][k];
            a0 += h0 * wd; a1 += h1v * wd; a2 += h2v * wd; a3 += h3v * wd;
            b0 += h0 * ws; b1 += h1v * ws; b2 += h2v * ws; b3 += h3v * ws;
        }
        A[(v0 + 0) * H + j] = a0;
        A[(v0 + 1) * H + j] = a1;
        A[(v0 + 2) * H + j] = a2;
        A[(v0 + 3) * H + j] = a3;
        B[(v0 + 0) * H + j] = b0;
        B[(v0 + 1) * H + j] = b1;
        B[(v0 + 2) * H + j] = b2;
        B[(v0 + 3) * H + j] = b3;
        __syncthreads();
    }
}

// ---------- per-node edge reduce: m2 = deg*r + sum_e relu(A[v]+B[src]+b_msg) ----------
// m2 aliases A (read A[v] before writing m2[v], same thread -> safe)
__global__ void k_edge(const int* __restrict__ offs, const int* __restrict__ eperm,
                       const int* __restrict__ esrc, const float* __restrict__ Afull,
                       const float* __restrict__ Bfull, const float* __restrict__ b_msg,
                       const float* __restrict__ r, const int* __restrict__ deg,
                       float* __restrict__ m2) {
    int v = blockIdx.x;
    int j = threadIdx.x; // 128
    float t = Afull[v * H + j] + b_msg[j];
    float acc = (float)deg[v] * r[j];
    int e0 = offs[v], e1 = offs[v + 1];
    for (int e = e0; e < e1; e++) {
        int src = esrc[eperm[e]];
        acc += fmaxf(t + Bfull[src * H + j], 0.f);
    }
    m2[v * H + j] = acc;
}

// ---------- h2 = tanh(m2@Wu_m + h1@Wu_h + xu + b_upd); ssum += sum_v h2 ----------
__global__ void k_h2sum(const float* __restrict__ m2, const float* __restrict__ h1,
                        const float* __restrict__ xu, const float* __restrict__ W_upd,
                        const float* __restrict__ b_upd, float* __restrict__ ssum) {
    __shared__ float ms[2][H], hs[2][H];
    int j = threadIdx.x; // 128
    float bu = b_upd[j];
    float sacc = 0.f;
    for (int v0 = blockIdx.x * 2; v0 < N_NODES; v0 += gridDim.x * 2) {
        for (int idx = j; idx < 2 * H; idx += 128) {
            int vv = idx >> 7, kk = idx & 127;
            ms[vv][kk] = m2[(v0 + vv) * H + kk];
            hs[vv][kk] = h1[(v0 + vv) * H + kk];
        }
        __syncthreads();
        float t0 = xu[(v0 + 0) * H + j] + bu;
        float t1 = xu[(v0 + 1) * H + j] + bu;
        for (int k = 0; k < H; k++) {
            float wm = W_upd[k * H + j];
            float wh = W_upd[(H + k) * H + j];
            t0 += ms[0][k] * wm + hs[0][k] * wh;
            t1 += ms[1][k] * wm + hs[1][k] * wh;
        }
        sacc += tanhf(t0) + tanhf(t1);
        __syncthreads();
    }
    atomicAdd(&ssum[j], sacc);
}

// ---------- out = relu(ssum @ W_ro + b_ro) ----------
__global__ void k_out(const float* __restrict__ ssum, const float* __restrict__ W_ro,
                      const float* __restrict__ b_ro, float* __restrict__ out) {
    int j = threadIdx.x; // 128
    __shared__ float ss[H];
    ss[j] = ssum[j];
    __syncthreads();
    float acc = b_ro[j];
    for (int k = 0; k < H; k++)
        acc += ss[k] * W_ro[k * H + j];
    out[j] = fmaxf(acc, 0.f);
}

extern "C" void kernel_launch(void* const* d_in, const int* in_sizes, int n_in,
                              void* d_out, int out_size, void* d_ws, size_t ws_size,
                              hipStream_t stream) {
    const float* data   = (const float*)d_in[0];
    const int*   esrc   = (const int*)d_in[1];
    const int*   edst   = (const int*)d_in[2];
    const float* W_emb  = (const float*)d_in[3];
    const float* b_emb  = (const float*)d_in[4];
    const float* W_msg  = (const float*)d_in[5];
    const float* b_msg  = (const float*)d_in[6];
    const float* W_upd  = (const float*)d_in[7];
    const float* b_upd  = (const float*)d_in[8];
    const float* W_ro   = (const float*)d_in[9];
    const float* b_ro   = (const float*)d_in[10];
    float* out = (float*)d_out;

    // workspace layout
    float* xu   = (float*)d_ws;          // N*H
    float* h1   = xu + N_NODES * H;      // N*H
    float* A    = h1 + N_NODES * H;      // N*H (becomes m2)
    float* B    = A + N_NODES * H;       // N*H
    float* r    = B + N_NODES * H;       // H
    float* c    = r + H;                 // H
    float* bx   = c + H;                 // H
    float* Wf   = bx + H;                // 64*H
    float* ssum = Wf + DATA_DIM * H;     // H
    int* degi   = (int*)(ssum + H);      // N
    int* offs   = degi + N_NODES;        // N+1
    int* cursor = offs + N_NODES + 1;    // N
    int* eperm  = cursor + N_NODES;      // E

    hipMemsetAsync(degi, 0, N_NODES * sizeof(int), stream);
    hipMemsetAsync(ssum, 0, H * sizeof(float), stream);

    k_pre<<<1, H, 0, stream>>>(b_emb, b_msg, W_upd, r, c, bx);
    k_wf<<<DATA_DIM, H, 0, stream>>>(W_emb, W_upd, Wf);
    k_deg<<<(N_EDGES + 255) / 256, 256, 0, stream>>>(edst, degi);
    k_scan<<<1, 1024, 0, stream>>>(degi, offs, cursor);
    k_scatter<<<(N_EDGES + 255) / 256, 256, 0, stream>>>(edst, cursor, eperm);
    k_xu<<<256, H, 0, stream>>>(data, Wf, bx, xu);
    k_h1<<<(N_NODES * H + 255) / 256, 256, 0, stream>>>(xu, degi, c, b_upd, h1);
    k_ab<<<256, H, 0, stream>>>(h1, W_msg, A, B);
    k_edge<<<N_NODES, H, 0, stream>>>(offs, eperm, esrc, A, B, b_msg, r, degi, A);
    k_h2sum<<<256, H, 0, stream>>>(A, h1, xu, W_upd, b_upd, ssum);
    k_out<<<1, H, 0, stream>>>(ssum, W_ro, b_ro, out);
}

// Round 2
// 265.587 us; speedup vs baseline: 2.2730x; 2.2730x over previous
//
#include <hip/hip_runtime.h>

#define N_NODES 20000
#define N_EDGES 320000
#define DATA_DIM 64
#define H 128

// ---------- tiny precompute: r = relu(b_msg); c = r @ Wu_m; bx = b_emb @ Wu_x ----------
__global__ void k_pre(const float* __restrict__ b_emb,
                      const float* __restrict__ b_msg,
                      const float* __restrict__ W_upd,
                      float* __restrict__ r, float* __restrict__ c,
                      float* __restrict__ bx) {
    int j = threadIdx.x; // 128
    __shared__ float rs[H];
    float rj = fmaxf(b_msg[j], 0.f);
    r[j] = rj;
    rs[j] = rj;
    __syncthreads();
    float cj = 0.f, bxj = 0.f;
    for (int k = 0; k < H; k++) {
        cj  += rs[k] * W_upd[k * H + j];            // Wu_m rows 0..127
        bxj += b_emb[k] * W_upd[(256 + k) * H + j]; // Wu_x rows 256..383
    }
    c[j] = cj;
    bx[j] = bxj;
}

// ---------- Wf = W_emb @ Wu_x  [64,128] ----------
__global__ void k_wf(const float* __restrict__ W_emb,
                     const float* __restrict__ W_upd,
                     float* __restrict__ Wf) {
    int d = blockIdx.x;  // 64 blocks
    int j = threadIdx.x; // 128
    __shared__ float es[H];
    es[j] = W_emb[d * H + j];
    __syncthreads();
    float acc = 0.f;
    for (int k = 0; k < H; k++)
        acc += es[k] * W_upd[(256 + k) * H + j];
    Wf[d * H + j] = acc;
}

// ---------- degree histogram over edge_dst ----------
__global__ void k_deg(const int* __restrict__ dst, int* __restrict__ deg) {
    int e = blockIdx.x * blockDim.x + threadIdx.x;
    if (e < N_EDGES) atomicAdd(&deg[dst[e]], 1);
}

// ---------- exclusive scan -> offs, cursor ----------
__global__ void k_scan(const int* __restrict__ deg, int* __restrict__ offs,
                       int* __restrict__ cursor) {
    __shared__ int buf[1024];
    int t = threadIdx.x;
    const int chunk = (N_NODES + 1023) / 1024; // 20
    int base = t * chunk;
    int s = 0;
    for (int i = 0; i < chunk; i++) {
        int idx = base + i;
        if (idx < N_NODES) s += deg[idx];
    }
    int val = s;
    for (int off = 1; off < 1024; off <<= 1) {
        buf[t] = val;
        __syncthreads();
        if (t >= off) val += buf[t - off];
        __syncthreads();
    }
    int run = val - s;
    for (int i = 0; i < chunk; i++) {
        int idx = base + i;
        if (idx < N_NODES) {
            offs[idx] = run;
            cursor[idx] = run;
            run += deg[idx];
        }
    }
    if (t == 1023) offs[N_NODES] = val;
}

// ---------- bucket-scatter SRC ids by dst (removes one indirection in k_edge) ----------
__global__ void k_scatter(const int* __restrict__ dst, const int* __restrict__ src,
                          int* __restrict__ cursor, int* __restrict__ srcp) {
    int e = blockIdx.x * blockDim.x + threadIdx.x;
    if (e < N_EDGES) {
        int p = atomicAdd(&cursor[dst[e]], 1);
        srcp[p] = src[e];
    }
}

// ---------- xu = data @ Wf + bx ; h1 = tanh(deg*c + xu + b_upd) ----------
__global__ void __launch_bounds__(256) k_xu_h1(
        const float* __restrict__ data, const float* __restrict__ Wf,
        const float* __restrict__ bx, const int* __restrict__ deg,
        const float* __restrict__ c, const float* __restrict__ b_upd,
        float* __restrict__ xu, float* __restrict__ h1) {
    __shared__ float ds[16][DATA_DIM]; // 4 KB
    int tid = threadIdx.x;
    int j = tid & 127, g = tid >> 7;
    int v0 = blockIdx.x * 16;
    for (int idx = tid; idx < 16 * DATA_DIM; idx += 256)
        ds[idx >> 6][idx & 63] = data[v0 * DATA_DIM + idx];
    __syncthreads();
    float acc[8] = {0, 0, 0, 0, 0, 0, 0, 0};
    #pragma unroll 4
    for (int k = 0; k < DATA_DIM; k++) {
        float w = Wf[k * H + j];
        #pragma unroll
        for (int i = 0; i < 8; i++)
            acc[i] += ds[g * 8 + i][k] * w;
    }
    float bxj = bx[j], cj = c[j], buj = b_upd[j];
    #pragma unroll
    for (int i = 0; i < 8; i++) {
        int v = v0 + g * 8 + i;
        float xv = acc[i] + bxj;
        xu[v * H + j] = xv;
        h1[v * H + j] = tanhf((float)deg[v] * cj + xv + buj);
    }
}

// ---------- A = h1 @ Wm_dst ; B = h1 @ Wm_src ----------
__global__ void __launch_bounds__(256) k_ab(
        const float* __restrict__ h1, const float* __restrict__ W_msg,
        float* __restrict__ A, float* __restrict__ B) {
    __shared__ float hs[16][H]; // 8 KB
    int tid = threadIdx.x;
    int j = tid & 127, g = tid >> 7;
    int v0 = blockIdx.x * 16;
    for (int idx = tid; idx < 16 * H; idx += 256)
        hs[idx >> 7][idx & 127] = h1[v0 * H + idx];
    __syncthreads();
    float a[8] = {0, 0, 0, 0, 0, 0, 0, 0};
    float b[8] = {0, 0, 0, 0, 0, 0, 0, 0};
    #pragma unroll 2
    for (int k = 0; k < H; k++) {
        float wd = W_msg[k * H + j];
        float ws = W_msg[(H + k) * H + j];
        #pragma unroll
        for (int i = 0; i < 8; i++) {
            float x = hs[g * 8 + i][k];
            a[i] += x * wd;
            b[i] += x * ws;
        }
    }
    #pragma unroll
    for (int i = 0; i < 8; i++) {
        int v = v0 + g * 8 + i;
        A[v * H + j] = a[i];
        B[v * H + j] = b[i];
    }
}

// ---------- per-node edge reduce: m2 = deg*r + sum_e relu(A[v]+B[src]+b_msg) ----------
// m2 aliases A (A[v] read before m2[v] written by the same thread group)
__global__ void __launch_bounds__(256) k_edge(
        const int* __restrict__ offs, const int* __restrict__ srcp,
        const float* __restrict__ Afull, const float* __restrict__ Bfull,
        const float* __restrict__ b_msg, const float* __restrict__ r,
        const int* __restrict__ deg, float* __restrict__ m2) {
    int tid = threadIdx.x;
    int j = tid & 127, g = tid >> 7;
    int v0 = blockIdx.x * 8;
    float bm = b_msg[j], rj = r[j];
    for (int it = 0; it < 4; it++) {
        int v = v0 + it * 2 + g;
        float t = Afull[v * H + j] + bm;
        float acc = (float)deg[v] * rj;
        int e = offs[v], e1 = offs[v + 1];
        for (; e + 4 <= e1; e += 4) {
            int s0 = srcp[e], s1 = srcp[e + 1], s2 = srcp[e + 2], s3 = srcp[e + 3];
            float x0 = Bfull[s0 * H + j];
            float x1 = Bfull[s1 * H + j];
            float x2 = Bfull[s2 * H + j];
            float x3 = Bfull[s3 * H + j];
            acc += fmaxf(t + x0, 0.f) + fmaxf(t + x1, 0.f)
                 + fmaxf(t + x2, 0.f) + fmaxf(t + x3, 0.f);
        }
        for (; e < e1; e++) {
            int s = srcp[e];
            acc += fmaxf(t + Bfull[s * H + j], 0.f);
        }
        m2[v * H + j] = acc;
    }
}

// ---------- h2 = tanh([m2|h1]@Wu + xu + b_upd); per-block partial column sums ----------
__global__ void __launch_bounds__(256) k_h2sum(
        const float* __restrict__ m2, const float* __restrict__ h1,
        const float* __restrict__ xu, const float* __restrict__ W_upd,
        const float* __restrict__ b_upd, float* __restrict__ partials) {
    __shared__ float xs[16][2 * H]; // 16 KB
    __shared__ float red[256];
    int tid = threadIdx.x;
    int j = tid & 127, g = tid >> 7;
    int v0 = blockIdx.x * 16;
    for (int idx = tid; idx < 16 * H; idx += 256) {
        xs[idx >> 7][idx & 127] = m2[v0 * H + idx];
        xs[idx >> 7][H + (idx & 127)] = h1[v0 * H + idx];
    }
    __syncthreads();
    float acc[8] = {0, 0, 0, 0, 0, 0, 0, 0};
    #pragma unroll 2
    for (int k = 0; k < 2 * H; k++) {
        float w = W_upd[k * H + j];
        #pragma unroll
        for (int i = 0; i < 8; i++)
            acc[i] += xs[g * 8 + i][k] * w;
    }
    float bu = b_upd[j];
    float s = 0.f;
    #pragma unroll
    for (int i = 0; i < 8; i++) {
        int v = v0 + g * 8 + i;
        s += tanhf(acc[i] + xu[v * H + j] + bu);
    }
    red[tid] = s;
    __syncthreads();
    if (g == 0)
        partials[blockIdx.x * H + j] = red[j] + red[H + j];
}

// ---------- reduce partials; out = relu(ssum @ W_ro + b_ro) ----------
__global__ void __launch_bounds__(1024) k_out(
        const float* __restrict__ partials, int nparts,
        const float* __restrict__ W_ro, const float* __restrict__ b_ro,
        float* __restrict__ out) {
    __shared__ float red[1024];
    __shared__ float ss[H];
    int tid = threadIdx.x;
    int j = tid & 127, g = tid >> 7; // 8 groups
    float s = 0.f;
    for (int b = g; b < nparts; b += 8)
        s += partials[b * H + j];
    red[tid] = s;
    __syncthreads();
    if (tid < H) {
        float tot = 0.f;
        #pragma unroll
        for (int q = 0; q < 8; q++)
            tot += red[q * H + tid];
        ss[tid] = tot;
    }
    __syncthreads();
    if (tid < H) {
        float acc = b_ro[tid];
        for (int k = 0; k < H; k++)
            acc += ss[k] * W_ro[k * H + tid];
        out[tid] = fmaxf(acc, 0.f);
    }
}

extern "C" void kernel_launch(void* const* d_in, const int* in_sizes, int n_in,
                              void* d_out, int out_size, void* d_ws, size_t ws_size,
                              hipStream_t stream) {
    const float* data   = (const float*)d_in[0];
    const int*   esrc   = (const int*)d_in[1];
    const int*   edst   = (const int*)d_in[2];
    const float* W_emb  = (const float*)d_in[3];
    const float* b_emb  = (const float*)d_in[4];
    const float* W_msg  = (const float*)d_in[5];
    const float* b_msg  = (const float*)d_in[6];
    const float* W_upd  = (const float*)d_in[7];
    const float* b_upd  = (const float*)d_in[8];
    const float* W_ro   = (const float*)d_in[9];
    const float* b_ro   = (const float*)d_in[10];
    float* out = (float*)d_out;

    const int NPART = N_NODES / 16; // 1250

    // workspace layout
    float* xu    = (float*)d_ws;           // N*H
    float* h1    = xu + N_NODES * H;       // N*H
    float* A     = h1 + N_NODES * H;       // N*H (becomes m2)
    float* B     = A + N_NODES * H;        // N*H
    float* part  = B + N_NODES * H;        // NPART*H
    float* r     = part + NPART * H;       // H
    float* c     = r + H;                  // H
    float* bx    = c + H;                  // H
    float* Wf    = bx + H;                 // 64*H
    int* degi    = (int*)(Wf + DATA_DIM * H); // N
    int* offs    = degi + N_NODES;         // N+1
    int* cursor  = offs + N_NODES + 1;     // N
    int* srcp    = cursor + N_NODES;       // E

    hipMemsetAsync(degi, 0, N_NODES * sizeof(int), stream);

    k_pre<<<1, H, 0, stream>>>(b_emb, b_msg, W_upd, r, c, bx);
    k_wf<<<DATA_DIM, H, 0, stream>>>(W_emb, W_upd, Wf);
    k_deg<<<(N_EDGES + 255) / 256, 256, 0, stream>>>(edst, degi);
    k_scan<<<1, 1024, 0, stream>>>(degi, offs, cursor);
    k_scatter<<<(N_EDGES + 255) / 256, 256, 0, stream>>>(edst, esrc, cursor, srcp);
    k_xu_h1<<<N_NODES / 16, 256, 0, stream>>>(data, Wf, bx, degi, c, b_upd, xu, h1);
    k_ab<<<N_NODES / 16, 256, 0, stream>>>(h1, W_msg, A, B);
    k_edge<<<N_NODES / 8, 256, 0, stream>>>(offs, srcp, A, B, b_msg, r, degi, A);
    k_h2sum<<<N_NODES / 16, 256, 0, stream>>>(A, h1, xu, W_upd, b_upd, part);
    k_out<<<1, 1024, 0, stream>>>(part, NPART, W_ro, b_ro, out);
}